// Round 1
// baseline (203.168 us; speedup 1.0000x reference)
//
#include <hip/hip_runtime.h>

#define T_DIM 1024
#define B_DIM 8
#define IN_DIM 1024
#define OUT_DIM 1024
#define N_MODL 16
#define K_SEL 2

typedef unsigned short ushort_t;
typedef __bf16 bf16x8 __attribute__((ext_vector_type(8)));
typedef float f32x4 __attribute__((ext_vector_type(4)));

__device__ __forceinline__ unsigned short f2bf(float f) {
  union { float f; unsigned int u; } v; v.f = f;
  unsigned int r = v.u + 0x7fffu + ((v.u >> 16) & 1u);  // RNE
  return (unsigned short)(r >> 16);
}

__device__ __forceinline__ void async_g2l(const void* g, void* l) {
  __builtin_amdgcn_global_load_lds(
      (const __attribute__((address_space(1))) unsigned int*)g,
      (__attribute__((address_space(3))) unsigned int*)l,
      16, 0, 0);
}

// x [T,B,IN] f32 -> xb [B,T,IN] bf16  (permute outer dims + convert; both sides coalesced)
__global__ __launch_bounds__(256) void convert_x_kernel(const float* __restrict__ x,
                                                        ushort_t* __restrict__ xb) {
  const int row = blockIdx.x;            // t*B + b
  const int t = row >> 3, b = row & 7;
  const float4* src = (const float4*)(x + (size_t)row * IN_DIM);
  ushort_t* dst = xb + ((size_t)b * T_DIM + t) * IN_DIM;
  float4 v = src[threadIdx.x];
  ushort4 o;
  o.x = f2bf(v.x); o.y = f2bf(v.y); o.z = f2bf(v.z); o.w = f2bf(v.w);
  *(ushort4*)(dst + threadIdx.x * 4) = o;
}

// W [16,IN,OUT] f32 -> Wt [16,OUT,IN] bf16 (LDS-tiled transpose + convert)
__global__ __launch_bounds__(256) void convert_w_kernel(const float* __restrict__ w,
                                                        ushort_t* __restrict__ wt) {
  __shared__ float tile[64][65];   // +1 pad: transpose-read conflict-free
  const int m = blockIdx.z;
  const int i0 = blockIdx.x * 64;
  const int o0 = blockIdx.y * 64;
  const float* src = w + ((size_t)m * IN_DIM + i0) * OUT_DIM + o0;
  const int c = (threadIdx.x & 15) * 4;
  const int r0 = threadIdx.x >> 4;
#pragma unroll
  for (int p = 0; p < 4; ++p) {
    const int r = r0 + p * 16;
    float4 v = *(const float4*)(src + (size_t)r * OUT_DIM + c);
    tile[r][c + 0] = v.x; tile[r][c + 1] = v.y;
    tile[r][c + 2] = v.z; tile[r][c + 3] = v.w;
  }
  __syncthreads();
  ushort_t* dst = wt + ((size_t)m * OUT_DIM + o0) * IN_DIM + i0;
#pragma unroll
  for (int p = 0; p < 4; ++p) {
    const int r = r0 + p * 16;     // o-local
    ushort4 ov;
    ov.x = f2bf(tile[c + 0][r]);
    ov.y = f2bf(tile[c + 1][r]);
    ov.z = f2bf(tile[c + 2][r]);
    ov.w = f2bf(tile[c + 3][r]);
    *(ushort4*)(dst + (size_t)r * IN_DIM + c) = ov;
  }
}

// Robust selection read: detect int64-LE (all odd 32b words of the 16 values zero)
__device__ __forceinline__ int read_sel(const int* __restrict__ s, int g) {
  bool i64 = true;
#pragma unroll
  for (int j = 0; j < 8; ++j) i64 &= (s[2 * j + 1] == 0);
  return i64 ? s[2 * g] : s[g];
}

// GEMM per (b,k): C[T,OUT] = xb[b] (T x IN) * Wt[sel]^T + bias[sel]
// 128x128 tile, BK=64, 256 threads = 4 waves, each wave 64x64 via 4x4 MFMA 16x16x32.
__global__ __launch_bounds__(256) void mlgemm_kernel(const ushort_t* __restrict__ xb,
                                                     const ushort_t* __restrict__ wt,
                                                     const int* __restrict__ selp,
                                                     const float* __restrict__ bias,
                                                     float* __restrict__ out) {
  __shared__ ushort_t As[128 * 64];  // [m][k] 16KB
  __shared__ ushort_t Bs[128 * 64];  // [n][k] 16KB (B^T layout)

  const int g = blockIdx.z;
  const int b = g >> 1, ks = g & 1;
  const int e = read_sel(selp, g);

  const ushort_t* A  = xb + (size_t)b * T_DIM * IN_DIM;
  const ushort_t* Bm = wt + (size_t)e * OUT_DIM * IN_DIM;
  const float* bp = bias + (size_t)e * OUT_DIM;

  const int m0 = blockIdx.y * 128;
  const int n0 = blockIdx.x * 128;

  const int tid = threadIdx.x;
  const int lane = tid & 63;
  const int wv = tid >> 6;

  // staging: chunk = 8 rows x 64 k = 1KB contiguous LDS; lane -> base + lane*16
  const int srow = lane >> 3;          // row within chunk
  const int scol = (lane & 7) * 8;     // k element offset
  const ushort_t* Abase = A  + (size_t)(m0 + srow) * IN_DIM + scol;
  const ushort_t* Bbase = Bm + (size_t)(n0 + srow) * IN_DIM + scol;

  // fragment read offsets (A-op: [m=lane&15][k=quad*8+j]; B-op same form on [n][k])
  const int frow = lane & 15;
  const int fk = (lane >> 4) * 8;
  const int wrow = (wv & 1) * 64;
  const int wcol = (wv >> 1) * 64;
  const ushort_t* Ard = As + (wrow + frow) * 64 + fk;
  const ushort_t* Brd = Bs + (wcol + frow) * 64 + fk;

  f32x4 acc[4][4] = {};

  for (int k0 = 0; k0 < IN_DIM; k0 += 64) {
#pragma unroll
    for (int c = 0; c < 4; ++c) {
      const int chunk = wv * 4 + c;            // 16 chunks of 8 rows cover 128 rows
      async_g2l(Abase + (size_t)chunk * 8 * IN_DIM + k0, As + chunk * 512);
      async_g2l(Bbase + (size_t)chunk * 8 * IN_DIM + k0, Bs + chunk * 512);
    }
    __syncthreads();   // drains vmcnt: staging visible
#pragma unroll
    for (int kk = 0; kk < 64; kk += 32) {
      bf16x8 af[4], bfr[4];
#pragma unroll
      for (int i = 0; i < 4; ++i) {
        af[i]  = *(const bf16x8*)(Ard + i * 16 * 64 + kk);
        bfr[i] = *(const bf16x8*)(Brd + i * 16 * 64 + kk);
      }
#pragma unroll
      for (int mt = 0; mt < 4; ++mt)
#pragma unroll
        for (int nt = 0; nt < 4; ++nt)
          acc[mt][nt] = __builtin_amdgcn_mfma_f32_16x16x32_bf16(af[mt], bfr[nt],
                                                                acc[mt][nt], 0, 0, 0);
    }
    __syncthreads();   // compute done before next-tile staging overwrites LDS
  }

  // epilogue: C/D map col=lane&15, row=(lane>>4)*4+reg
  const int orow0 = m0 + wrow + ((lane >> 4) * 4);
  const int ocol0 = n0 + wcol + (lane & 15);
  float bv[4];
#pragma unroll
  for (int nt = 0; nt < 4; ++nt) bv[nt] = bp[ocol0 + nt * 16];
  float* Cb = out + (size_t)b * (K_SEL * OUT_DIM) + (size_t)ks * OUT_DIM;
#pragma unroll
  for (int mt = 0; mt < 4; ++mt) {
#pragma unroll
    for (int r = 0; r < 4; ++r) {
      const size_t rowoff = (size_t)(orow0 + mt * 16 + r) * (B_DIM * K_SEL * OUT_DIM);
#pragma unroll
      for (int nt = 0; nt < 4; ++nt)
        Cb[rowoff + ocol0 + nt * 16] = acc[mt][nt][r] + bv[nt];
    }
  }
}

extern "C" void kernel_launch(void* const* d_in, const int* in_sizes, int n_in,
                              void* d_out, int out_size, void* d_ws, size_t ws_size,
                              hipStream_t stream) {
  const float* x    = (const float*)d_in[0];
  const int*   sel  = (const int*)d_in[1];
  const float* w    = (const float*)d_in[2];
  const float* bias = (const float*)d_in[3];
  float* out = (float*)d_out;

  ushort_t* xb = (ushort_t*)d_ws;                                   // 16 MB
  ushort_t* wt = (ushort_t*)((char*)d_ws +
                             (size_t)B_DIM * T_DIM * IN_DIM * 2);   // +16 MB, 32 MB

  convert_x_kernel<<<dim3(T_DIM * B_DIM), 256, 0, stream>>>(x, xb);
  convert_w_kernel<<<dim3(IN_DIM / 64, OUT_DIM / 64, N_MODL), 256, 0, stream>>>(w, wt);
  mlgemm_kernel<<<dim3(OUT_DIM / 128, T_DIM / 128, B_DIM * K_SEL), 256, 0, stream>>>(
      xb, wt, sel, bias, out);
}

// Round 2
// 186.908 us; speedup vs baseline: 1.0870x; 1.0870x over previous
//
#include <hip/hip_runtime.h>

#define T_DIM 1024
#define B_DIM 8
#define IN_DIM 1024
#define OUT_DIM 1024
#define N_MODL 16
#define K_SEL 2

typedef unsigned short ushort_t;
typedef __bf16 bf16x8 __attribute__((ext_vector_type(8)));
typedef float f32x4 __attribute__((ext_vector_type(4)));

__device__ __forceinline__ unsigned int f2bf2(float lo, float hi) {
  union { float f; unsigned int u; } a, b; a.f = lo; b.f = hi;
  unsigned int ra = (a.u + 0x7fffu + ((a.u >> 16) & 1u)) >> 16;
  unsigned int rb = (b.u + 0x7fffu + ((b.u >> 16) & 1u)) >> 16;
  return ra | (rb << 16);
}
__device__ __forceinline__ unsigned short f2bf(float f) {
  union { float f; unsigned int u; } v; v.f = f;
  return (unsigned short)((v.u + 0x7fffu + ((v.u >> 16) & 1u)) >> 16);
}

__device__ __forceinline__ void async_g2l(const void* g, void* l) {
  __builtin_amdgcn_global_load_lds(
      (const __attribute__((address_space(1))) unsigned int*)g,
      (__attribute__((address_space(3))) unsigned int*)l,
      16, 0, 0);
}

// x [T,B,IN] f32 -> bf16, same order (no transpose; GEMM handles row stride).
// Each thread: 32B read, 16B write.
__global__ __launch_bounds__(256) void convert_x_kernel(const float* __restrict__ x,
                                                        ushort_t* __restrict__ xb) {
  const int i = blockIdx.x * 256 + threadIdx.x;   // 8 floats per thread
  const float4* s = (const float4*)x;
  float4 a = s[i * 2], b = s[i * 2 + 1];
  uint4 o;
  o.x = f2bf2(a.x, a.y); o.y = f2bf2(a.z, a.w);
  o.z = f2bf2(b.x, b.y); o.w = f2bf2(b.z, b.w);
  ((uint4*)xb)[i] = o;
}

// W [16,IN,OUT] f32 -> Wt [16,OUT,IN] bf16 (LDS-tiled transpose + convert)
__global__ __launch_bounds__(256) void convert_w_kernel(const float* __restrict__ w,
                                                        ushort_t* __restrict__ wt) {
  __shared__ float tile[64][65];
  const int m = blockIdx.z;
  const int i0 = blockIdx.x * 64;
  const int o0 = blockIdx.y * 64;
  const float* src = w + ((size_t)m * IN_DIM + i0) * OUT_DIM + o0;
  const int c = (threadIdx.x & 15) * 4;
  const int r0 = threadIdx.x >> 4;
#pragma unroll
  for (int p = 0; p < 4; ++p) {
    const int r = r0 + p * 16;
    float4 v = *(const float4*)(src + (size_t)r * OUT_DIM + c);
    tile[r][c + 0] = v.x; tile[r][c + 1] = v.y;
    tile[r][c + 2] = v.z; tile[r][c + 3] = v.w;
  }
  __syncthreads();
  ushort_t* dst = wt + ((size_t)m * OUT_DIM + o0) * IN_DIM + i0;
#pragma unroll
  for (int p = 0; p < 4; ++p) {
    const int r = r0 + p * 16;     // o-local
    ushort4 ov;
    ov.x = f2bf(tile[c + 0][r]);
    ov.y = f2bf(tile[c + 1][r]);
    ov.z = f2bf(tile[c + 2][r]);
    ov.w = f2bf(tile[c + 3][r]);
    *(ushort4*)(dst + (size_t)r * IN_DIM + c) = ov;
  }
}

__device__ __forceinline__ int read_sel(const int* __restrict__ s, int g) {
  bool i64 = true;
#pragma unroll
  for (int j = 0; j < 8; ++j) i64 &= (s[2 * j + 1] == 0);
  return i64 ? s[2 * g] : s[g];
}

// GEMM per (b,k): C[T,OUT] = x[:,b,:] (T x IN) * Wt[sel]^T + bias[sel]
// 128x128 tile, BK=64, 4 waves x (64x64 via 4x4 MFMA 16x16x32).
// LDS layout XOR-swizzled: slot(r,c) = r*8 + (c ^ (r&7)), 16B chunks,
// so quad-uniform-k fragment reads spread across all 8 bank groups.
__global__ __launch_bounds__(256, 4) void mlgemm_kernel(const ushort_t* __restrict__ xb,
                                                        const ushort_t* __restrict__ wt,
                                                        const int* __restrict__ selp,
                                                        const float* __restrict__ bias,
                                                        float* __restrict__ out) {
  __shared__ ushort_t As[128 * 64];  // 16KB, swizzled chunks
  __shared__ ushort_t Bs[128 * 64];  // 16KB, swizzled chunks

  const int g = blockIdx.z;
  const int b = g >> 1, ks = g & 1;
  const int e = read_sel(selp, g);

  const ushort_t* A  = xb + (size_t)b * IN_DIM;         // row t at + t*B*IN
  const ushort_t* Bm = wt + (size_t)e * OUT_DIM * IN_DIM;
  const float* bp = bias + (size_t)e * OUT_DIM;

  const int m0 = blockIdx.y * 128;
  const int n0 = blockIdx.x * 128;

  const int tid = threadIdx.x;
  const int lane = tid & 63;
  const int wv = tid >> 6;

  // staging: region j = 8 rows x 8 chunks = 64 slots; lane l -> slot j*64+l
  //   local row = l>>3, swizzled chunk = l&7, actual chunk = (l&7)^((l>>3)&7)
  const int srow = lane >> 3;
  const int sx = (((lane & 7) ^ (srow & 7)) << 3);      // element offset in row
  const ushort_t* Ab = A  + (size_t)(m0 + srow) * (B_DIM * IN_DIM) + sx;
  const ushort_t* Bb = Bm + (size_t)(n0 + srow) * IN_DIM + sx;

  // fragment: A[m=lane&15][k=quad*8+j]; swizzled element offset in row:
  //   ((quad ^ (row&7) ^ kk/8) * 8)
  const int frow = lane & 15;
  const int quad = lane >> 4;
  const int cbase = ((quad ^ (frow & 7)) << 3);
  const int wrow = (wv & 1) * 64;
  const int wcol = (wv >> 1) * 64;
  const ushort_t* Ard = As + (wrow + frow) * 64;
  const ushort_t* Brd = Bs + (wcol + frow) * 64;

  f32x4 acc[4][4] = {};

  for (int k0 = 0; k0 < IN_DIM; k0 += 64) {
#pragma unroll
    for (int c = 0; c < 4; ++c) {
      const int j = wv * 4 + c;                 // 16 regions cover 128 rows
      async_g2l(Ab + (size_t)(8 * j) * (B_DIM * IN_DIM) + k0, As + j * 512);
      async_g2l(Bb + (size_t)(8 * j) * IN_DIM + k0, Bs + j * 512);
    }
    __syncthreads();   // compiler emits vmcnt(0) drain: staging visible
#pragma unroll
    for (int kk = 0; kk < 64; kk += 32) {
      const int coff = cbase ^ kk;              // kk in {0,32} = chunk bit 2
      bf16x8 af[4], bfr[4];
#pragma unroll
      for (int i = 0; i < 4; ++i) {
        af[i]  = *(const bf16x8*)(Ard + i * 16 * 64 + coff);
        bfr[i] = *(const bf16x8*)(Brd + i * 16 * 64 + coff);
      }
#pragma unroll
      for (int mt = 0; mt < 4; ++mt)
#pragma unroll
        for (int nt = 0; nt < 4; ++nt)
          acc[mt][nt] = __builtin_amdgcn_mfma_f32_16x16x32_bf16(af[mt], bfr[nt],
                                                                acc[mt][nt], 0, 0, 0);
    }
    __syncthreads();
  }

  // epilogue: C/D map col=lane&15, row=(lane>>4)*4+reg
  const int orow0 = m0 + wrow + (quad * 4);
  const int ocol0 = n0 + wcol + frow;
  float bv[4];
#pragma unroll
  for (int nt = 0; nt < 4; ++nt) bv[nt] = bp[ocol0 + nt * 16];
  float* Cb = out + (size_t)b * (K_SEL * OUT_DIM) + (size_t)ks * OUT_DIM;
#pragma unroll
  for (int mt = 0; mt < 4; ++mt) {
#pragma unroll
    for (int r = 0; r < 4; ++r) {
      const size_t rowoff = (size_t)(orow0 + mt * 16 + r) * (B_DIM * K_SEL * OUT_DIM);
#pragma unroll
      for (int nt = 0; nt < 4; ++nt)
        Cb[rowoff + ocol0 + nt * 16] = acc[mt][nt][r] + bv[nt];
    }
  }
}

extern "C" void kernel_launch(void* const* d_in, const int* in_sizes, int n_in,
                              void* d_out, int out_size, void* d_ws, size_t ws_size,
                              hipStream_t stream) {
  const float* x    = (const float*)d_in[0];
  const int*   sel  = (const int*)d_in[1];
  const float* w    = (const float*)d_in[2];
  const float* bias = (const float*)d_in[3];
  float* out = (float*)d_out;

  ushort_t* xb = (ushort_t*)d_ws;                                   // 16 MB
  ushort_t* wt = (ushort_t*)((char*)d_ws +
                             (size_t)T_DIM * B_DIM * IN_DIM * 2);   // +16 MB

  convert_x_kernel<<<dim3(T_DIM * B_DIM * IN_DIM / 8 / 256), 256, 0, stream>>>(x, xb);
  convert_w_kernel<<<dim3(IN_DIM / 64, OUT_DIM / 64, N_MODL), 256, 0, stream>>>(w, wt);
  mlgemm_kernel<<<dim3(OUT_DIM / 128, T_DIM / 128, B_DIM * K_SEL), 256, 0, stream>>>(
      xb, wt, sel, bias, out);
}

// Round 3
// 183.499 us; speedup vs baseline: 1.1072x; 1.0186x over previous
//
#include <hip/hip_runtime.h>

#define T_DIM 1024
#define B_DIM 8
#define IN_DIM 1024
#define OUT_DIM 1024
#define N_MODL 16
#define K_SEL 2

typedef unsigned short ushort_t;
typedef __bf16 bf16x8 __attribute__((ext_vector_type(8)));
typedef float f32x4 __attribute__((ext_vector_type(4)));

__device__ __forceinline__ unsigned int f2bf2(float lo, float hi) {
  union { float f; unsigned int u; } a, b; a.f = lo; b.f = hi;
  unsigned int ra = (a.u + 0x7fffu + ((a.u >> 16) & 1u)) >> 16;
  unsigned int rb = (b.u + 0x7fffu + ((b.u >> 16) & 1u)) >> 16;
  return ra | (rb << 16);
}
__device__ __forceinline__ unsigned short f2bf(float f) {
  union { float f; unsigned int u; } v; v.f = f;
  return (unsigned short)((v.u + 0x7fffu + ((v.u >> 16) & 1u)) >> 16);
}

__device__ __forceinline__ void async_g2l(const void* g, void* l) {
  __builtin_amdgcn_global_load_lds(
      (const __attribute__((address_space(1))) unsigned int*)g,
      (__attribute__((address_space(3))) unsigned int*)l,
      16, 0, 0);
}

// Merged prep kernel: blocks [0,4096) transpose+convert W, blocks [4096,4608)
// stream-convert x. Branch is block-uniform (no divergence).
__global__ __launch_bounds__(256) void convert_kernel(const float* __restrict__ x,
                                                      const float* __restrict__ w,
                                                      ushort_t* __restrict__ xb,
                                                      ushort_t* __restrict__ wt) {
  __shared__ float tile[64][65];
  const int bid = blockIdx.x;
  if (bid >= 4096) {
    // x [T,B,IN] f32 -> bf16 same order; 8 floats (32B read / 16B write) per thread
    const int i = (bid - 4096) * 256 + threadIdx.x;
    const float4* s = (const float4*)x;
    float4 a = s[i * 2], b = s[i * 2 + 1];
    uint4 o;
    o.x = f2bf2(a.x, a.y); o.y = f2bf2(a.z, a.w);
    o.z = f2bf2(b.x, b.y); o.w = f2bf2(b.z, b.w);
    ((uint4*)xb)[i] = o;
    return;
  }
  // W [16,IN,OUT] f32 -> Wt [16,OUT,IN] bf16, LDS-tiled 64x64 transpose
  const int m = bid >> 8;
  const int rest = bid & 255;
  const int i0 = (rest & 15) * 64;
  const int o0 = (rest >> 4) * 64;
  const float* src = w + ((size_t)m * IN_DIM + i0) * OUT_DIM + o0;
  const int c = (threadIdx.x & 15) * 4;
  const int r0 = threadIdx.x >> 4;
#pragma unroll
  for (int p = 0; p < 4; ++p) {
    const int r = r0 + p * 16;
    float4 v = *(const float4*)(src + (size_t)r * OUT_DIM + c);
    tile[r][c + 0] = v.x; tile[r][c + 1] = v.y;
    tile[r][c + 2] = v.z; tile[r][c + 3] = v.w;
  }
  __syncthreads();
  ushort_t* dst = wt + ((size_t)m * OUT_DIM + o0) * IN_DIM + i0;
#pragma unroll
  for (int p = 0; p < 4; ++p) {
    const int r = r0 + p * 16;     // o-local
    ushort4 ov;
    ov.x = f2bf(tile[c + 0][r]);
    ov.y = f2bf(tile[c + 1][r]);
    ov.z = f2bf(tile[c + 2][r]);
    ov.w = f2bf(tile[c + 3][r]);
    *(ushort4*)(dst + (size_t)r * IN_DIM + c) = ov;
  }
}

__device__ __forceinline__ int read_sel(const int* __restrict__ s, int g) {
  bool i64 = true;
#pragma unroll
  for (int j = 0; j < 8; ++j) i64 &= (s[2 * j + 1] == 0);
  return i64 ? s[2 * g] : s[g];
}

// Fused sibling GEMMs: per b, C[T, e0-cols] and C[T, e1-cols] share the A
// operand. One block = 128x128 m/n tile for BOTH experts: stage As once,
// Bs[2], 2x MFMA per barrier. LDS 48KB, XOR-swizzled 16B chunks (0 conflicts).
__global__ __launch_bounds__(256, 2) void mlgemm_kernel(const ushort_t* __restrict__ xb,
                                                        const ushort_t* __restrict__ wt,
                                                        const int* __restrict__ selp,
                                                        const float* __restrict__ bias,
                                                        float* __restrict__ out) {
  __shared__ ushort_t As[128 * 64];      // 16KB
  __shared__ ushort_t Bs[2][128 * 64];   // 32KB

  const int b = blockIdx.z;
  const int e0 = read_sel(selp, 2 * b);
  const int e1 = read_sel(selp, 2 * b + 1);

  const ushort_t* A  = xb + (size_t)b * IN_DIM;          // row t at + t*B*IN
  const ushort_t* B0 = wt + (size_t)e0 * OUT_DIM * IN_DIM;
  const ushort_t* B1 = wt + (size_t)e1 * OUT_DIM * IN_DIM;

  const int m0 = blockIdx.y * 128;
  const int n0 = blockIdx.x * 128;

  const int lane = threadIdx.x & 63;
  const int wv = threadIdx.x >> 6;

  // staging: region j = 8 rows x 8 swizzled 16B chunks; lane l -> slot j*64+l
  const int srow = lane >> 3;
  const int sx = (((lane & 7) ^ (srow & 7)) << 3);
  const ushort_t* Ab  = A  + (size_t)(m0 + srow) * (B_DIM * IN_DIM) + sx;
  const ushort_t* Bb0 = B0 + (size_t)(n0 + srow) * IN_DIM + sx;
  const ushort_t* Bb1 = B1 + (size_t)(n0 + srow) * IN_DIM + sx;

  // fragment: A[m=lane&15][k=quad*8+j]; swizzled chunk = quad ^ (row&7) ^ kk/8
  const int frow = lane & 15;
  const int quad = lane >> 4;
  const int cbase = ((quad ^ (frow & 7)) << 3);
  const int wrow = (wv & 1) * 64;
  const int wcol = (wv >> 1) * 64;
  const ushort_t* Ard  = As    + (wrow + frow) * 64;
  const ushort_t* Brd0 = Bs[0] + (wcol + frow) * 64;
  const ushort_t* Brd1 = Bs[1] + (wcol + frow) * 64;

  f32x4 acc0[4][4] = {};
  f32x4 acc1[4][4] = {};

  for (int k0 = 0; k0 < IN_DIM; k0 += 64) {
#pragma unroll
    for (int c = 0; c < 4; ++c) {
      const int j = wv * 4 + c;                 // 16 regions cover 128 rows
      async_g2l(Ab  + (size_t)(8 * j) * (B_DIM * IN_DIM) + k0, As + j * 512);
      async_g2l(Bb0 + (size_t)(8 * j) * IN_DIM + k0, Bs[0] + j * 512);
      async_g2l(Bb1 + (size_t)(8 * j) * IN_DIM + k0, Bs[1] + j * 512);
    }
    __syncthreads();   // vmcnt(0) drain: staging visible
#pragma unroll
    for (int kk = 0; kk < 64; kk += 32) {
      const int coff = cbase ^ kk;
      bf16x8 af[4], bf0[4], bf1[4];
#pragma unroll
      for (int i = 0; i < 4; ++i) {
        af[i]  = *(const bf16x8*)(Ard  + i * 16 * 64 + coff);
        bf0[i] = *(const bf16x8*)(Brd0 + i * 16 * 64 + coff);
        bf1[i] = *(const bf16x8*)(Brd1 + i * 16 * 64 + coff);
      }
#pragma unroll
      for (int mt = 0; mt < 4; ++mt)
#pragma unroll
        for (int nt = 0; nt < 4; ++nt) {
          acc0[mt][nt] = __builtin_amdgcn_mfma_f32_16x16x32_bf16(af[mt], bf0[nt],
                                                                 acc0[mt][nt], 0, 0, 0);
          acc1[mt][nt] = __builtin_amdgcn_mfma_f32_16x16x32_bf16(af[mt], bf1[nt],
                                                                 acc1[mt][nt], 0, 0, 0);
        }
    }
    __syncthreads();
  }

  // epilogue: C/D map col=lane&15, row=quad*4+reg
  const int orow0 = m0 + wrow + quad * 4;
  const int ocol0 = n0 + wcol + frow;
  const float* bp0 = bias + (size_t)e0 * OUT_DIM;
  const float* bp1 = bias + (size_t)e1 * OUT_DIM;
  float bv0[4], bv1[4];
#pragma unroll
  for (int nt = 0; nt < 4; ++nt) {
    bv0[nt] = bp0[ocol0 + nt * 16];
    bv1[nt] = bp1[ocol0 + nt * 16];
  }
  float* C0 = out + (size_t)b * (K_SEL * OUT_DIM);
  float* C1 = C0 + OUT_DIM;
#pragma unroll
  for (int mt = 0; mt < 4; ++mt) {
#pragma unroll
    for (int r = 0; r < 4; ++r) {
      const size_t rowoff = (size_t)(orow0 + mt * 16 + r) * (B_DIM * K_SEL * OUT_DIM);
#pragma unroll
      for (int nt = 0; nt < 4; ++nt) {
        C0[rowoff + ocol0 + nt * 16] = acc0[mt][nt][r] + bv0[nt];
        C1[rowoff + ocol0 + nt * 16] = acc1[mt][nt][r] + bv1[nt];
      }
    }
  }
}

extern "C" void kernel_launch(void* const* d_in, const int* in_sizes, int n_in,
                              void* d_out, int out_size, void* d_ws, size_t ws_size,
                              hipStream_t stream) {
  const float* x    = (const float*)d_in[0];
  const int*   sel  = (const int*)d_in[1];
  const float* w    = (const float*)d_in[2];
  const float* bias = (const float*)d_in[3];
  float* out = (float*)d_out;

  ushort_t* xb = (ushort_t*)d_ws;                                   // 16 MB
  ushort_t* wt = (ushort_t*)((char*)d_ws +
                             (size_t)T_DIM * B_DIM * IN_DIM * 2);   // +32 MB

  convert_kernel<<<dim3(4096 + T_DIM * B_DIM * IN_DIM / 8 / 256), 256, 0, stream>>>(
      x, w, xb, wt);
  mlgemm_kernel<<<dim3(OUT_DIM / 128, T_DIM / 128, B_DIM), 256, 0, stream>>>(
      xb, wt, sel, bias, out);
}

// Round 4
// 175.910 us; speedup vs baseline: 1.1550x; 1.0431x over previous
//
#include <hip/hip_runtime.h>

#define T_DIM 1024
#define B_DIM 8
#define IN_DIM 1024
#define OUT_DIM 1024
#define N_MODL 16
#define K_SEL 2

typedef unsigned short ushort_t;
typedef __bf16 bf16x8 __attribute__((ext_vector_type(8)));
typedef float f32x4 __attribute__((ext_vector_type(4)));

__device__ __forceinline__ unsigned int f2bf2(float lo, float hi) {
  union { float f; unsigned int u; } a, b; a.f = lo; b.f = hi;
  unsigned int ra = (a.u + 0x7fffu + ((a.u >> 16) & 1u)) >> 16;
  unsigned int rb = (b.u + 0x7fffu + ((b.u >> 16) & 1u)) >> 16;
  return ra | (rb << 16);
}

__device__ __forceinline__ void async_g2l(const void* g, void* l) {
  __builtin_amdgcn_global_load_lds(
      (const __attribute__((address_space(1))) unsigned int*)g,
      (__attribute__((address_space(3))) unsigned int*)l,
      16, 0, 0);
}

__device__ __forceinline__ int read_sel(const int* __restrict__ s, int g) {
  bool i64 = true;
#pragma unroll
  for (int j = 0; j < 8; ++j) i64 &= (s[2 * j + 1] == 0);
  return i64 ? s[2 * g] : s[g];
}

// Blocks [0,1024): W [16,IN,OUT] f32 -> Wt [16,OUT,IN] bf16, 128x128 tiles,
//   bf16-in-LDS with XOR swizzle, 512B read / 256B write segments, skipping
//   experts not present in `selection`.
// Blocks [1024,5120): x [T,B,IN] f32 -> bf16 stream convert (same layout).
__global__ __launch_bounds__(256) void convert_kernel(const float* __restrict__ x,
                                                      const float* __restrict__ w,
                                                      const int* __restrict__ selp,
                                                      ushort_t* __restrict__ xb,
                                                      ushort_t* __restrict__ wt) {
  __shared__ ushort_t tb[128 * 128];   // 32KB
  const int bid = blockIdx.x;
  if (bid >= 1024) {
    // x stream convert: 8 floats (32B read / 16B write) per thread
    const int i = (bid - 1024) * 256 + threadIdx.x;
    const float4* s = (const float4*)x;
    float4 a = s[i * 2], b = s[i * 2 + 1];
    uint4 o;
    o.x = f2bf2(a.x, a.y); o.y = f2bf2(a.z, a.w);
    o.z = f2bf2(b.x, b.y); o.w = f2bf2(b.z, b.w);
    ((uint4*)xb)[i] = o;
    return;
  }
  const int m = bid >> 6;
  // skip experts nobody selected (block-uniform; deterministic per launch)
  bool used = false;
#pragma unroll
  for (int g = 0; g < B_DIM * K_SEL; ++g) used |= (read_sel(selp, g) == m);
  if (!used) return;

  const int i0 = ((bid >> 3) & 7) * 128;
  const int o0 = (bid & 7) * 128;
  const float* src = w + ((size_t)(m * IN_DIM + i0)) * OUT_DIM + o0;

  // phase 1: load fp32 (512B segments), convert, swizzled LDS write (8B)
  const int o4 = (threadIdx.x & 31) * 4;
  const int ib = threadIdx.x >> 5;               // 0..7
#pragma unroll
  for (int p = 0; p < 16; ++p) {
    const int i = ib + p * 8;
    float4 v = *(const float4*)(src + (size_t)i * OUT_DIM + o4);
    const int osw = o4 ^ (((i >> 3) & 15) << 2); // swizzle o bits 2-5 by i>>3
    uint2 d2; d2.x = f2bf2(v.x, v.y); d2.y = f2bf2(v.z, v.w);
    *(uint2*)(tb + i * 128 + osw) = d2;
  }
  __syncthreads();

  // phase 2: column-gather from LDS (16 distinct banks), 16B global stores
  ushort_t* dst = wt + ((size_t)(m * OUT_DIM + o0)) * IN_DIM + i0;
  const int il = (threadIdx.x & 15) * 8;         // i-chunk of 8
  const int ob = threadIdx.x >> 4;               // 0..15
  const int q2 = ((il >> 3) & 15) << 2;          // swizzle term (const per thread)
#pragma unroll
  for (int p = 0; p < 8; ++p) {
    const int o = ob + p * 16;
    const int osw = o ^ q2;
    uint4 d;
    unsigned int u[8];
#pragma unroll
    for (int j = 0; j < 8; ++j) u[j] = tb[(il + j) * 128 + osw];
    d.x = u[0] | (u[1] << 16); d.y = u[2] | (u[3] << 16);
    d.z = u[4] | (u[5] << 16); d.w = u[6] | (u[7] << 16);
    *(uint4*)(dst + (size_t)o * IN_DIM + il) = d;
  }
}

// Fused sibling GEMMs per b (both experts share the A operand). 128x128 tile,
// BK=64, 4 waves x 64x64 x 2 experts. XOR-swizzled LDS (0 conflicts).
// 1D grid, b = lin&7 -> per-XCD L2 residency of A and both B experts.
__global__ __launch_bounds__(256, 2) void mlgemm_kernel(const ushort_t* __restrict__ xb,
                                                        const ushort_t* __restrict__ wt,
                                                        const int* __restrict__ selp,
                                                        const float* __restrict__ bias,
                                                        float* __restrict__ out) {
  __shared__ ushort_t As[128 * 64];      // 16KB
  __shared__ ushort_t Bs[2][128 * 64];   // 32KB

  const int lin = blockIdx.x;
  const int b = lin & 7;                 // XCD = lin % 8 (heuristic)
  const int mtile = (lin >> 3) & 7;
  const int ntile = lin >> 6;
  const int e0 = read_sel(selp, 2 * b);
  const int e1 = read_sel(selp, 2 * b + 1);

  const ushort_t* A  = xb + (size_t)b * IN_DIM;          // row t at + t*B*IN
  const ushort_t* B0 = wt + (size_t)e0 * OUT_DIM * IN_DIM;
  const ushort_t* B1 = wt + (size_t)e1 * OUT_DIM * IN_DIM;

  const int m0 = mtile * 128;
  const int n0 = ntile * 128;

  const int lane = threadIdx.x & 63;
  const int wv = threadIdx.x >> 6;

  // staging: region j = 8 rows x 8 swizzled 16B chunks; lane l -> slot j*64+l
  const int srow = lane >> 3;
  const int sx = (((lane & 7) ^ (srow & 7)) << 3);
  const ushort_t* Ab  = A  + (size_t)(m0 + srow) * (B_DIM * IN_DIM) + sx;
  const ushort_t* Bb0 = B0 + (size_t)(n0 + srow) * IN_DIM + sx;
  const ushort_t* Bb1 = B1 + (size_t)(n0 + srow) * IN_DIM + sx;

  // fragment: A[m=lane&15][k=quad*8+j]; swizzled chunk = quad ^ (row&7) ^ kk/8
  const int frow = lane & 15;
  const int quad = lane >> 4;
  const int cbase = ((quad ^ (frow & 7)) << 3);
  const int wrow = (wv & 1) * 64;
  const int wcol = (wv >> 1) * 64;
  const ushort_t* Ard  = As    + (wrow + frow) * 64;
  const ushort_t* Brd0 = Bs[0] + (wcol + frow) * 64;
  const ushort_t* Brd1 = Bs[1] + (wcol + frow) * 64;

  f32x4 acc0[4][4] = {};
  f32x4 acc1[4][4] = {};

  for (int k0 = 0; k0 < IN_DIM; k0 += 64) {
#pragma unroll
    for (int c = 0; c < 4; ++c) {
      const int j = wv * 4 + c;                 // 16 regions cover 128 rows
      async_g2l(Ab  + (size_t)(8 * j) * (B_DIM * IN_DIM) + k0, As + j * 512);
      async_g2l(Bb0 + (size_t)(8 * j) * IN_DIM + k0, Bs[0] + j * 512);
      async_g2l(Bb1 + (size_t)(8 * j) * IN_DIM + k0, Bs[1] + j * 512);
    }
    __syncthreads();   // vmcnt(0) drain: staging visible
#pragma unroll
    for (int kk = 0; kk < 64; kk += 32) {
      const int coff = cbase ^ kk;
      bf16x8 af[4], bf0[4], bf1[4];
#pragma unroll
      for (int i = 0; i < 4; ++i) {
        af[i]  = *(const bf16x8*)(Ard  + i * 16 * 64 + coff);
        bf0[i] = *(const bf16x8*)(Brd0 + i * 16 * 64 + coff);
        bf1[i] = *(const bf16x8*)(Brd1 + i * 16 * 64 + coff);
      }
#pragma unroll
      for (int mt = 0; mt < 4; ++mt)
#pragma unroll
        for (int nt = 0; nt < 4; ++nt) {
          acc0[mt][nt] = __builtin_amdgcn_mfma_f32_16x16x32_bf16(af[mt], bf0[nt],
                                                                 acc0[mt][nt], 0, 0, 0);
          acc1[mt][nt] = __builtin_amdgcn_mfma_f32_16x16x32_bf16(af[mt], bf1[nt],
                                                                 acc1[mt][nt], 0, 0, 0);
        }
    }
    __syncthreads();
  }

  // epilogue: C/D map col=lane&15, row=quad*4+reg
  const int orow0 = m0 + wrow + quad * 4;
  const int ocol0 = n0 + wcol + frow;
  const float* bp0 = bias + (size_t)e0 * OUT_DIM;
  const float* bp1 = bias + (size_t)e1 * OUT_DIM;
  float bv0[4], bv1[4];
#pragma unroll
  for (int nt = 0; nt < 4; ++nt) {
    bv0[nt] = bp0[ocol0 + nt * 16];
    bv1[nt] = bp1[ocol0 + nt * 16];
  }
  float* C0 = out + (size_t)b * (K_SEL * OUT_DIM);
  float* C1 = C0 + OUT_DIM;
#pragma unroll
  for (int mt = 0; mt < 4; ++mt) {
#pragma unroll
    for (int r = 0; r < 4; ++r) {
      const size_t rowoff = (size_t)(orow0 + mt * 16 + r) * (B_DIM * K_SEL * OUT_DIM);
#pragma unroll
      for (int nt = 0; nt < 4; ++nt) {
        C0[rowoff + ocol0 + nt * 16] = acc0[mt][nt][r] + bv0[nt];
        C1[rowoff + ocol0 + nt * 16] = acc1[mt][nt][r] + bv1[nt];
      }
    }
  }
}

extern "C" void kernel_launch(void* const* d_in, const int* in_sizes, int n_in,
                              void* d_out, int out_size, void* d_ws, size_t ws_size,
                              hipStream_t stream) {
  const float* x    = (const float*)d_in[0];
  const int*   sel  = (const int*)d_in[1];
  const float* w    = (const float*)d_in[2];
  const float* bias = (const float*)d_in[3];
  float* out = (float*)d_out;

  ushort_t* xb = (ushort_t*)d_ws;                                   // 16 MB
  ushort_t* wt = (ushort_t*)((char*)d_ws +
                             (size_t)T_DIM * B_DIM * IN_DIM * 2);   // +32 MB

  convert_kernel<<<dim3(1024 + T_DIM * B_DIM * IN_DIM / 8 / 256), 256, 0, stream>>>(
      x, w, sel, xb, wt);
  mlgemm_kernel<<<dim3(8 * 8 * B_DIM), 256, 0, stream>>>(xb, wt, sel, bias, out);
}